// Round 1
// baseline (242.088 us; speedup 1.0000x reference)
//
#include <hip/hip_runtime.h>

typedef short bf16x8 __attribute__((ext_vector_type(8)));
typedef float f32x4 __attribute__((ext_vector_type(4)));

#define NB 2
#define NN 20000
#define ME 320000
#define STRIPES 64

__device__ __forceinline__ unsigned short f2bf(float f) {
  union { float f; unsigned int u; } v; v.f = f;
  unsigned int r = (v.u + 0x7FFFu + ((v.u >> 16) & 1u)) >> 16;  // RNE
  return (unsigned short)r;
}

__device__ __forceinline__ f32x4 mfma16(bf16x8 a, bf16x8 b, f32x4 c) {
  return __builtin_amdgcn_mfma_f32_16x16x32_bf16(a, b, c, 0, 0, 0);
}

// ---------------- conversion kernels ----------------

__global__ void cvt_x_kernel(const float* __restrict__ X, short* __restrict__ Xbf) {
  int i = blockIdx.x * 256 + threadIdx.x;  // 640000 threads, 8 elems each
  const float4* p = reinterpret_cast<const float4*>(X) + (size_t)i * 2;
  float4 a = p[0], b = p[1];
  bf16x8 v;
  v[0]=(short)f2bf(a.x); v[1]=(short)f2bf(a.y); v[2]=(short)f2bf(a.z); v[3]=(short)f2bf(a.w);
  v[4]=(short)f2bf(b.x); v[5]=(short)f2bf(b.y); v[6]=(short)f2bf(b.z); v[7]=(short)f2bf(b.w);
  reinterpret_cast<bf16x8*>(Xbf)[i] = v;
}

// transpose weights to [col][k] bf16 with zero K-padding (272->288, 16->32)
__global__ void prep_w_kernel(const float* __restrict__ eW1, const float* __restrict__ eW2,
                              const float* __restrict__ nW1, const float* __restrict__ nW2,
                              const float* __restrict__ pW,
                              short* __restrict__ ew1T, short* __restrict__ ew2T,
                              short* __restrict__ nw1T, short* __restrict__ nw2T,
                              short* __restrict__ pwT) {
  int c = blockIdx.x;   // 0..127 (output col)
  int t = threadIdx.x;  // 256
  for (int k = t; k < 288; k += 256)
    ew1T[c * 288 + k] = (k < 272) ? (short)f2bf(eW1[(size_t)k * 128 + c]) : (short)0;
  if (t < 128) {
    ew2T[c * 128 + t] = (short)f2bf(eW2[(size_t)t * 128 + c]);
    nw1T[c * 128 + t] = (short)f2bf(nW1[(size_t)t * 128 + c]);
    nw2T[c * 128 + t] = (short)f2bf(nW2[(size_t)t * 128 + c]);
  }
  if (t < 32) pwT[c * 32 + t] = (t < 16) ? (short)f2bf(pW[(size_t)t * 128 + c]) : (short)0;
}

// ---------------- edge MLP kernel ----------------
// per block: 4 tiles of 64 edges; 4 waves, wave w owns output cols [32w,32w+32)
// accumulates sum_e relu(MLP)*gate (m), sum_e gate*(E@pW) (p), sum_e gate

template<bool XBF>
__global__ __launch_bounds__(256, 2) void edge_kernel(
    const short* __restrict__ Xbf, const float* __restrict__ X,
    const float* __restrict__ E, const int* __restrict__ edges,
    const short* __restrict__ ew1T, const short* __restrict__ ew2T,
    const short* __restrict__ pwT, const float* __restrict__ eb1,
    const float* __restrict__ eb2, const float* __restrict__ gsp,
    float* __restrict__ edge_acc) {
  __shared__ __align__(16) short A_lds[64 * 296];   // 64 edges x K=288 (pitch 296)
  __shared__ __align__(16) short h1_lds[64 * 136];  // 64 x 128 (pitch 136)
  __shared__ float gate_lds[64];

  const int tid = threadIdx.x;
  const int lane = tid & 63;
  const int w = tid >> 6;
  const int fc = lane & 15;   // frag col / A-row slot
  const int fg = lane >> 4;   // k-group
  const int ncol0 = w * 32;
  const int b = blockIdx.y;

  const float gs = gsp[0];
  const float* E_b = E + (size_t)b * ME * 16;
  const int* edges_b = edges + (size_t)b * ME * 2;
  const short* Xbf_b = Xbf + (size_t)b * NN * 128;
  const float* X_b = X + (size_t)b * NN * 128;

  // persistent B fragments in VGPRs
  bf16x8 B1[2][9], B2[2][4], PWf[2];
  float eb1v[2], eb2v[2];
#pragma unroll
  for (int nt = 0; nt < 2; ++nt) {
    int col = ncol0 + nt * 16 + fc;
#pragma unroll
    for (int kt = 0; kt < 9; ++kt)
      B1[nt][kt] = *reinterpret_cast<const bf16x8*>(ew1T + col * 288 + kt * 32 + fg * 8);
#pragma unroll
    for (int kt = 0; kt < 4; ++kt)
      B2[nt][kt] = *reinterpret_cast<const bf16x8*>(ew2T + col * 128 + kt * 32 + fg * 8);
    PWf[nt] = *reinterpret_cast<const bf16x8*>(pwT + col * 32 + fg * 8);
    eb1v[nt] = eb1[col];
    eb2v[nt] = eb2[col];
  }

  float accm0 = 0.f, accm1 = 0.f, accp0 = 0.f, accp1 = 0.f, accg = 0.f;

  for (int it = 0; it < 4; ++it) {
    const int t = blockIdx.x * 4 + it;  // 0..4999
    const int e0 = t * 64;
    // ---- stage eij tile: [X[src] | X[dst] | E | 0pad] ----
    if (XBF) {
#pragma unroll
      for (int p = 0; p < 8; ++p) {
        int row = p * 16 + (tid >> 4);  // 0..127: 0-63 src rows, 64-127 dst rows
        int chunk = tid & 15;
        int e = row & 63, half = row >> 6;
        int node = edges_b[(size_t)(e0 + e) * 2 + half];
        uint4 v = reinterpret_cast<const uint4*>(Xbf_b + (size_t)node * 128)[chunk];
        *reinterpret_cast<uint4*>(&A_lds[e * 296 + half * 128 + chunk * 8]) = v;
      }
    } else {
#pragma unroll
      for (int p = 0; p < 16; ++p) {
        int slot = p * 256 + tid;
        int row = slot >> 5, chunk = slot & 31;
        int e = row & 63, half = row >> 6;
        int node = edges_b[(size_t)(e0 + e) * 2 + half];
        float4 f = reinterpret_cast<const float4*>(X_b + (size_t)node * 128)[chunk];
        ushort4 v; v.x = f2bf(f.x); v.y = f2bf(f.y); v.z = f2bf(f.z); v.w = f2bf(f.w);
        *reinterpret_cast<ushort4*>(&A_lds[e * 296 + half * 128 + chunk * 4]) = v;
      }
    }
    if (tid < 128) {  // E features (k 256..271)
      int e = tid >> 1, half = tid & 1;
      const float4* pe = reinterpret_cast<const float4*>(E_b + (size_t)(e0 + e) * 16 + half * 8);
      float4 f0 = pe[0], f1 = pe[1];
      bf16x8 v;
      v[0]=(short)f2bf(f0.x); v[1]=(short)f2bf(f0.y); v[2]=(short)f2bf(f0.z); v[3]=(short)f2bf(f0.w);
      v[4]=(short)f2bf(f1.x); v[5]=(short)f2bf(f1.y); v[6]=(short)f2bf(f1.z); v[7]=(short)f2bf(f1.w);
      *reinterpret_cast<bf16x8*>(&A_lds[e * 296 + 256 + half * 8]) = v;
    } else {          // zero pad (k 272..287)
      int e2 = (tid - 128) >> 1, half2 = (tid - 128) & 1;
      bf16x8 z = {0, 0, 0, 0, 0, 0, 0, 0};
      *reinterpret_cast<bf16x8*>(&A_lds[e2 * 296 + 272 + half2 * 8]) = z;
    }
    if (tid < 64) {
      float e2v = E_b[(size_t)(e0 + tid) * 16 + 2];
      gate_lds[tid] = fminf(fmaxf(1.f + gs * e2v, 0.f), 3.f);
    }
    __syncthreads();
    if (w == 0) accg += gate_lds[lane];

    f32x4 zf = {0.f, 0.f, 0.f, 0.f};
    // ---- layer 1 (K=288) + pW (reuse k=256..287 A-frag) ----
#pragma unroll
    for (int rt = 0; rt < 4; ++rt) {
      const short* arow = &A_lds[(rt * 16 + fc) * 296 + fg * 8];
      f32x4 a0 = zf, a1 = zf;
#pragma unroll
      for (int kt = 0; kt < 9; ++kt) {
        bf16x8 av = *reinterpret_cast<const bf16x8*>(arow + kt * 32);
        a0 = mfma16(av, B1[0][kt], a0);
        a1 = mfma16(av, B1[1][kt], a1);
      }
      bf16x8 av8 = *reinterpret_cast<const bf16x8*>(arow + 256);
      f32x4 p0 = mfma16(av8, PWf[0], zf);
      f32x4 p1 = mfma16(av8, PWf[1], zf);
#pragma unroll
      for (int r = 0; r < 4; ++r) {
        int row = rt * 16 + fg * 4 + r;  // C/D: row=(lane>>4)*4+reg
        float g = gate_lds[row];
        accp0 += p0[r] * g;
        accp1 += p1[r] * g;
        h1_lds[row * 136 + ncol0 + fc] = (short)f2bf(fmaxf(a0[r] + eb1v[0], 0.f));
        h1_lds[row * 136 + ncol0 + 16 + fc] = (short)f2bf(fmaxf(a1[r] + eb1v[1], 0.f));
      }
    }
    __syncthreads();
    // ---- layer 2 (K=128) ----
#pragma unroll
    for (int rt = 0; rt < 4; ++rt) {
      const short* hrow = &h1_lds[(rt * 16 + fc) * 136 + fg * 8];
      f32x4 a0 = zf, a1 = zf;
#pragma unroll
      for (int kt = 0; kt < 4; ++kt) {
        bf16x8 hv = *reinterpret_cast<const bf16x8*>(hrow + kt * 32);
        a0 = mfma16(hv, B2[0][kt], a0);
        a1 = mfma16(hv, B2[1][kt], a1);
      }
#pragma unroll
      for (int r = 0; r < 4; ++r) {
        int row = rt * 16 + fg * 4 + r;
        float g = gate_lds[row];
        accm0 += fmaxf(a0[r] + eb2v[0], 0.f) * g;
        accm1 += fmaxf(a1[r] + eb2v[1], 0.f) * g;
      }
    }
    __syncthreads();
  }

  // ---- reduce over fg groups, striped atomics ----
  accm0 += __shfl_xor(accm0, 16); accm0 += __shfl_xor(accm0, 32);
  accm1 += __shfl_xor(accm1, 16); accm1 += __shfl_xor(accm1, 32);
  accp0 += __shfl_xor(accp0, 16); accp0 += __shfl_xor(accp0, 32);
  accp1 += __shfl_xor(accp1, 16); accp1 += __shfl_xor(accp1, 32);
  const int stripe = blockIdx.x & (STRIPES - 1);
  float* base = edge_acc + ((size_t)b * STRIPES + stripe) * 264;
  if (fg == 0) {
    atomicAdd(base + ncol0 + fc, accm0);
    atomicAdd(base + ncol0 + 16 + fc, accm1);
    atomicAdd(base + 128 + ncol0 + fc, accp0);
    atomicAdd(base + 128 + ncol0 + 16 + fc, accp1);
  }
  if (w == 0) {
#pragma unroll
    for (int off = 1; off < 64; off <<= 1) accg += __shfl_xor(accg, off);
    if (lane == 0) atomicAdd(base + 256, accg);
  }
}

// ---------------- node MLP kernel (sum of Hx over nodes) ----------------

template<bool XBF>
__global__ __launch_bounds__(256, 2) void node_kernel(
    const short* __restrict__ Xbf, const float* __restrict__ X,
    const short* __restrict__ nw1T, const short* __restrict__ nw2T,
    const float* __restrict__ nb1, const float* __restrict__ nb2,
    float* __restrict__ node_acc) {
  __shared__ __align__(16) short A_lds[64 * 136];
  __shared__ __align__(16) short h1_lds[64 * 136];
  const int tid = threadIdx.x;
  const int lane = tid & 63;
  const int w = tid >> 6;
  const int fc = lane & 15;
  const int fg = lane >> 4;
  const int ncol0 = w * 32;
  const int b = blockIdx.y;
  const short* Xbf_b = Xbf + (size_t)b * NN * 128;
  const float* X_b = X + (size_t)b * NN * 128;

  bf16x8 B1[2][4], B2[2][4];
  float b1v[2], b2v[2];
#pragma unroll
  for (int nt = 0; nt < 2; ++nt) {
    int col = ncol0 + nt * 16 + fc;
#pragma unroll
    for (int kt = 0; kt < 4; ++kt) {
      B1[nt][kt] = *reinterpret_cast<const bf16x8*>(nw1T + col * 128 + kt * 32 + fg * 8);
      B2[nt][kt] = *reinterpret_cast<const bf16x8*>(nw2T + col * 128 + kt * 32 + fg * 8);
    }
    b1v[nt] = nb1[col];
    b2v[nt] = nb2[col];
  }
  float acc0 = 0.f, acc1 = 0.f;
  for (int t = blockIdx.x; t < 313; t += 157) {
    const int n0 = t * 64;
    if (XBF) {
#pragma unroll
      for (int p = 0; p < 4; ++p) {
        int row = p * 16 + (tid >> 4);
        int chunk = tid & 15;
        int node = n0 + row;
        uint4 v = {0, 0, 0, 0};
        if (node < NN) v = reinterpret_cast<const uint4*>(Xbf_b + (size_t)node * 128)[chunk];
        *reinterpret_cast<uint4*>(&A_lds[row * 136 + chunk * 8]) = v;
      }
    } else {
#pragma unroll
      for (int p = 0; p < 8; ++p) {
        int slot = p * 256 + tid;
        int row = slot >> 5, chunk = slot & 31;
        int node = n0 + row;
        ushort4 v = {0, 0, 0, 0};
        if (node < NN) {
          float4 f = reinterpret_cast<const float4*>(X_b + (size_t)node * 128)[chunk];
          v.x = f2bf(f.x); v.y = f2bf(f.y); v.z = f2bf(f.z); v.w = f2bf(f.w);
        }
        *reinterpret_cast<ushort4*>(&A_lds[row * 136 + chunk * 4]) = v;
      }
    }
    __syncthreads();
    f32x4 zf = {0.f, 0.f, 0.f, 0.f};
#pragma unroll
    for (int rt = 0; rt < 4; ++rt) {
      const short* arow = &A_lds[(rt * 16 + fc) * 136 + fg * 8];
      f32x4 a0 = zf, a1 = zf;
#pragma unroll
      for (int kt = 0; kt < 4; ++kt) {
        bf16x8 av = *reinterpret_cast<const bf16x8*>(arow + kt * 32);
        a0 = mfma16(av, B1[0][kt], a0);
        a1 = mfma16(av, B1[1][kt], a1);
      }
#pragma unroll
      for (int r = 0; r < 4; ++r) {
        int row = rt * 16 + fg * 4 + r;
        h1_lds[row * 136 + ncol0 + fc] = (short)f2bf(fmaxf(a0[r] + b1v[0], 0.f));
        h1_lds[row * 136 + ncol0 + 16 + fc] = (short)f2bf(fmaxf(a1[r] + b1v[1], 0.f));
      }
    }
    __syncthreads();
#pragma unroll
    for (int rt = 0; rt < 4; ++rt) {
      const short* hrow = &h1_lds[(rt * 16 + fc) * 136 + fg * 8];
      f32x4 a0 = zf, a1 = zf;
#pragma unroll
      for (int kt = 0; kt < 4; ++kt) {
        bf16x8 hv = *reinterpret_cast<const bf16x8*>(hrow + kt * 32);
        a0 = mfma16(hv, B2[0][kt], a0);
        a1 = mfma16(hv, B2[1][kt], a1);
      }
#pragma unroll
      for (int r = 0; r < 4; ++r) {
        int row = n0 + rt * 16 + fg * 4 + r;
        if (row < NN) {
          acc0 += fmaxf(a0[r] + b2v[0], 0.f);
          acc1 += fmaxf(a1[r] + b2v[1], 0.f);
        }
      }
    }
    __syncthreads();
  }
  acc0 += __shfl_xor(acc0, 16); acc0 += __shfl_xor(acc0, 32);
  acc1 += __shfl_xor(acc1, 16); acc1 += __shfl_xor(acc1, 32);
  if (fg == 0) {
    const int stripe = blockIdx.x & (STRIPES - 1);
    float* base = node_acc + ((size_t)b * STRIPES + stripe) * 128;
    atomicAdd(base + ncol0 + fc, acc0);
    atomicAdd(base + ncol0 + 16 + fc, acc1);
  }
}

// ---------------- final combine + readout head (exact f32) ----------------

__global__ void final_kernel(const float* __restrict__ edge_acc, const float* __restrict__ node_acc,
                             const float* __restrict__ pb, const float* __restrict__ rW1,
                             const float* __restrict__ rb1, const float* __restrict__ rW2,
                             const float* __restrict__ rb2, float* __restrict__ out) {
  int b = blockIdx.x;
  int j = threadIdx.x;  // 0..127
  __shared__ float feat[256];
  __shared__ float h[64];
  const float* ea = edge_acc + (size_t)b * STRIPES * 264;
  const float* na = node_acc + (size_t)b * STRIPES * 128;
  float ms = 0.f, ps = 0.f, hs = 0.f, gsum = 0.f;
  for (int s = 0; s < STRIPES; ++s) {
    ms += ea[s * 264 + j];
    ps += ea[s * 264 + 128 + j];
    hs += na[s * 128 + j];
    gsum += ea[s * 264 + 256];
  }
  feat[j] = (hs + 2.f * ms) * (1.f / (float)NN);          // H.mean = Hx.mean + 2*sum_m/N
  feat[128 + j] = (ps + gsum * pb[j]) / ((float)ME + 1e-6f);
  __syncthreads();
  if (j < 64) {
    float a = rb1[j];
    for (int i = 0; i < 256; ++i) a += feat[i] * rW1[i * 64 + j];
    h[j] = fmaxf(a, 0.f);
  }
  __syncthreads();
  if (j < 2) {
    float a = rb2[j];
    for (int i = 0; i < 64; ++i) a += h[i] * rW2[i * 2 + j];
    out[b * 2 + j] = a;
  }
}

// ---------------- host ----------------

extern "C" void kernel_launch(void* const* d_in, const int* in_sizes, int n_in,
                              void* d_out, int out_size, void* d_ws, size_t ws_size,
                              hipStream_t stream) {
  const float* X = (const float*)d_in[0];
  const float* E = (const float*)d_in[1];
  const int* edges = (const int*)d_in[2];
  const float* nW1 = (const float*)d_in[3];
  const float* nb1 = (const float*)d_in[4];
  const float* nW2 = (const float*)d_in[5];
  const float* nb2 = (const float*)d_in[6];
  const float* eW1 = (const float*)d_in[7];
  const float* eb1 = (const float*)d_in[8];
  const float* eW2 = (const float*)d_in[9];
  const float* eb2 = (const float*)d_in[10];
  const float* pW = (const float*)d_in[11];
  const float* pb = (const float*)d_in[12];
  const float* rW1 = (const float*)d_in[13];
  const float* rb1 = (const float*)d_in[14];
  const float* rW2 = (const float*)d_in[15];
  const float* rb2 = (const float*)d_in[16];
  const float* gscale = (const float*)d_in[17];
  float* out = (float*)d_out;

  char* ws = (char*)d_ws;
  size_t off = 0;
  auto alloc = [&](size_t sz) -> void* {
    void* p = ws + off;
    off = (off + sz + 255) & ~(size_t)255;
    return p;
  };
  short* ew1T = (short*)alloc(288 * 128 * 2);
  short* ew2T = (short*)alloc(128 * 128 * 2);
  short* nw1T = (short*)alloc(128 * 128 * 2);
  short* nw2T = (short*)alloc(128 * 128 * 2);
  short* pwT  = (short*)alloc(32 * 128 * 2);
  size_t acc_floats = (size_t)NB * STRIPES * 264 + (size_t)NB * STRIPES * 128;
  float* acc = (float*)alloc(acc_floats * 4);
  float* edge_acc = acc;
  float* node_acc = acc + (size_t)NB * STRIPES * 264;
  size_t xbf_bytes = (size_t)NB * NN * 128 * 2;
  size_t off_before_xbf = off;
  short* Xbf = (short*)alloc(xbf_bytes);
  bool use_xbf = (off_before_xbf + xbf_bytes) <= ws_size;

  hipMemsetAsync(acc, 0, acc_floats * 4, stream);
  prep_w_kernel<<<dim3(128), dim3(256), 0, stream>>>(eW1, eW2, nW1, nW2, pW,
                                                     ew1T, ew2T, nw1T, nw2T, pwT);
  if (use_xbf) {
    cvt_x_kernel<<<dim3(2500), dim3(256), 0, stream>>>(X, Xbf);
    edge_kernel<true><<<dim3(1250, 2), dim3(256), 0, stream>>>(
        Xbf, X, E, edges, ew1T, ew2T, pwT, eb1, eb2, gscale, edge_acc);
    node_kernel<true><<<dim3(157, 2), dim3(256), 0, stream>>>(
        Xbf, X, nw1T, nw2T, nb1, nb2, node_acc);
  } else {
    edge_kernel<false><<<dim3(1250, 2), dim3(256), 0, stream>>>(
        Xbf, X, E, edges, ew1T, ew2T, pwT, eb1, eb2, gscale, edge_acc);
    node_kernel<false><<<dim3(157, 2), dim3(256), 0, stream>>>(
        Xbf, X, nw1T, nw2T, nb1, nb2, node_acc);
  }
  final_kernel<<<dim3(NB), dim3(128), 0, stream>>>(edge_acc, node_acc, pb, rW1, rb1, rW2, rb2, out);
}

// Round 3
// 235.408 us; speedup vs baseline: 1.0284x; 1.0284x over previous
//
#include <hip/hip_runtime.h>

typedef short bf16x8 __attribute__((ext_vector_type(8)));
typedef float f32x4 __attribute__((ext_vector_type(4)));

#define NB 2
#define NN 20000
#define ME 320000
#define STRIPES 64
#define NT 8  // tiles (64 edges) per edge-kernel block

__device__ __forceinline__ unsigned short f2bf(float f) {
  union { float f; unsigned int u; } v; v.f = f;
  unsigned int r = (v.u + 0x7FFFu + ((v.u >> 16) & 1u)) >> 16;  // RNE
  return (unsigned short)r;
}

__device__ __forceinline__ bf16x8 pack2(float4 a, float4 b) {
  bf16x8 v;
  v[0]=(short)f2bf(a.x); v[1]=(short)f2bf(a.y); v[2]=(short)f2bf(a.z); v[3]=(short)f2bf(a.w);
  v[4]=(short)f2bf(b.x); v[5]=(short)f2bf(b.y); v[6]=(short)f2bf(b.z); v[7]=(short)f2bf(b.w);
  return v;
}

__device__ __forceinline__ f32x4 mfma16(bf16x8 a, bf16x8 b, f32x4 c) {
  return __builtin_amdgcn_mfma_f32_16x16x32_bf16(a, b, c, 0, 0, 0);
}

// transpose weights to [col][k] bf16 with zero K-padding (272->288, 16->32)
__global__ void prep_w_kernel(const float* __restrict__ eW1, const float* __restrict__ eW2,
                              const float* __restrict__ nW1, const float* __restrict__ nW2,
                              const float* __restrict__ pW,
                              short* __restrict__ ew1T, short* __restrict__ ew2T,
                              short* __restrict__ nw1T, short* __restrict__ nw2T,
                              short* __restrict__ pwT) {
  int c = blockIdx.x;   // 0..127 (output col)
  int t = threadIdx.x;  // 256
  for (int k = t; k < 288; k += 256)
    ew1T[c * 288 + k] = (k < 272) ? (short)f2bf(eW1[(size_t)k * 128 + c]) : (short)0;
  if (t < 128) {
    ew2T[c * 128 + t] = (short)f2bf(eW2[(size_t)t * 128 + c]);
    nw1T[c * 128 + t] = (short)f2bf(nW1[(size_t)t * 128 + c]);
    nw2T[c * 128 + t] = (short)f2bf(nW2[(size_t)t * 128 + c]);
  }
  if (t < 32) pwT[c * 32 + t] = (t < 16) ? (short)f2bf(pW[(size_t)t * 128 + c]) : (short)0;
}

// ---------------- node MLP kernel: sum of Hx over nodes; optionally emits Xbf ----------------

template<bool WRITEBF>
__global__ __launch_bounds__(256, 2) void node_kernel(
    const float* __restrict__ X, short* __restrict__ Xbf,
    const short* __restrict__ nw1T, const short* __restrict__ nw2T,
    const float* __restrict__ nb1, const float* __restrict__ nb2,
    float* __restrict__ node_acc) {
  __shared__ __align__(16) short A_lds[64 * 136];
  __shared__ __align__(16) short h1_lds[64 * 136];
  const int tid = threadIdx.x;
  const int lane = tid & 63;
  const int w = tid >> 6;
  const int fc = lane & 15;
  const int fg = lane >> 4;
  const int ncol0 = w * 32;
  const int b = blockIdx.y;
  const float* X_b = X + (size_t)b * NN * 128;
  short* Xbf_b = Xbf + (size_t)b * NN * 128;

  bf16x8 B1[2][4], B2[2][4];
  float b1v[2], b2v[2];
#pragma unroll
  for (int nt = 0; nt < 2; ++nt) {
    int col = ncol0 + nt * 16 + fc;
#pragma unroll
    for (int kt = 0; kt < 4; ++kt) {
      B1[nt][kt] = *reinterpret_cast<const bf16x8*>(nw1T + col * 128 + kt * 32 + fg * 8);
      B2[nt][kt] = *reinterpret_cast<const bf16x8*>(nw2T + col * 128 + kt * 32 + fg * 8);
    }
    b1v[nt] = nb1[col];
    b2v[nt] = nb2[col];
  }

  const int n0 = blockIdx.x * 64;  // 313 blocks cover 20032 rows (tail guarded)
#pragma unroll
  for (int p = 0; p < 8; ++p) {
    int slot = p * 256 + tid;
    int row = slot >> 5, chunk = slot & 31;
    int node = n0 + row;
    ushort4 v = {0, 0, 0, 0};
    if (node < NN) {
      float4 f = *reinterpret_cast<const float4*>(X_b + (size_t)node * 128 + chunk * 4);
      v.x = f2bf(f.x); v.y = f2bf(f.y); v.z = f2bf(f.z); v.w = f2bf(f.w);
      if (WRITEBF) *reinterpret_cast<ushort4*>(Xbf_b + (size_t)node * 128 + chunk * 4) = v;
    }
    *reinterpret_cast<ushort4*>(&A_lds[row * 136 + chunk * 4]) = v;
  }
  __syncthreads();

  f32x4 zf = {0.f, 0.f, 0.f, 0.f};
  float acc0 = 0.f, acc1 = 0.f;
#pragma unroll
  for (int rt = 0; rt < 4; ++rt) {
    const short* arow = &A_lds[(rt * 16 + fc) * 136 + fg * 8];
    f32x4 a0 = zf, a1 = zf;
#pragma unroll
    for (int kt = 0; kt < 4; ++kt) {
      bf16x8 av = *reinterpret_cast<const bf16x8*>(arow + kt * 32);
      a0 = mfma16(av, B1[0][kt], a0);
      a1 = mfma16(av, B1[1][kt], a1);
    }
#pragma unroll
    for (int r = 0; r < 4; ++r) {
      int row = rt * 16 + fg * 4 + r;
      h1_lds[row * 136 + ncol0 + fc] = (short)f2bf(fmaxf(a0[r] + b1v[0], 0.f));
      h1_lds[row * 136 + ncol0 + 16 + fc] = (short)f2bf(fmaxf(a1[r] + b1v[1], 0.f));
    }
  }
  __syncthreads();
#pragma unroll
  for (int rt = 0; rt < 4; ++rt) {
    const short* hrow = &h1_lds[(rt * 16 + fc) * 136 + fg * 8];
    f32x4 a0 = zf, a1 = zf;
#pragma unroll
    for (int kt = 0; kt < 4; ++kt) {
      bf16x8 hv = *reinterpret_cast<const bf16x8*>(hrow + kt * 32);
      a0 = mfma16(hv, B2[0][kt], a0);
      a1 = mfma16(hv, B2[1][kt], a1);
    }
#pragma unroll
    for (int r = 0; r < 4; ++r) {
      int row = n0 + rt * 16 + fg * 4 + r;
      if (row < NN) {
        acc0 += fmaxf(a0[r] + b2v[0], 0.f);
        acc1 += fmaxf(a1[r] + b2v[1], 0.f);
      }
    }
  }
  acc0 += __shfl_xor(acc0, 16); acc0 += __shfl_xor(acc0, 32);
  acc1 += __shfl_xor(acc1, 16); acc1 += __shfl_xor(acc1, 32);
  if (fg == 0) {
    const int stripe = blockIdx.x & (STRIPES - 1);
    float* base = node_acc + ((size_t)b * STRIPES + stripe) * 128;
    atomicAdd(base + ncol0 + fc, acc0);
    atomicAdd(base + ncol0 + 16 + fc, acc1);
  }
}

// ---------------- edge MLP kernel (software-pipelined, 2 barriers/tile) ----------------
// phase A: prefetch tile t+1 (E, gathers -> 8 named bf16x8 regs) + idx t+2; layer1 MFMA on tile t
// phase B: drain prefetch into LDS; layer2 MFMA on h1

template<bool XBF>
__global__ __launch_bounds__(256, 2) void edge_kernel(
    const short* __restrict__ Xbf, const float* __restrict__ X,
    const float* __restrict__ E, const int* __restrict__ edges,
    const short* __restrict__ ew1T, const short* __restrict__ ew2T,
    const short* __restrict__ pwT, const float* __restrict__ eb1,
    const float* __restrict__ eb2, const float* __restrict__ gsp,
    float* __restrict__ edge_acc) {
  __shared__ __align__(16) short A_lds[64 * 296];   // 64 edges x K=288 (pitch 296 = 37 granules, b128-balanced)
  __shared__ __align__(16) short h1_lds[64 * 136];
  __shared__ float gate_lds[2][64];
  __shared__ int idx_lds[2][128];

  const int tid = threadIdx.x;
  const int lane = tid & 63;
  const int w = tid >> 6;
  const int fc = lane & 15;
  const int fg = lane >> 4;
  const int ncol0 = w * 32;
  const int b = blockIdx.y;

  const float gs = gsp[0];
  const float* E_b = E + (size_t)b * ME * 16;
  const int* edges_b = edges + (size_t)b * ME * 2;
  const short* Xbf_b = Xbf + (size_t)b * NN * 128;
  const float* X_b = X + (size_t)b * NN * 128;
  const int tile0 = blockIdx.x * NT;

  // persistent B fragments in VGPRs
  bf16x8 B1[2][9], B2[2][4], PWf[2];
  float eb1v[2], eb2v[2];
#pragma unroll
  for (int nt = 0; nt < 2; ++nt) {
    int col = ncol0 + nt * 16 + fc;
#pragma unroll
    for (int kt = 0; kt < 9; ++kt)
      B1[nt][kt] = *reinterpret_cast<const bf16x8*>(ew1T + col * 288 + kt * 32 + fg * 8);
#pragma unroll
    for (int kt = 0; kt < 4; ++kt)
      B2[nt][kt] = *reinterpret_cast<const bf16x8*>(ew2T + col * 128 + kt * 32 + fg * 8);
    PWf[nt] = *reinterpret_cast<const bf16x8*>(pwT + col * 32 + fg * 8);
    eb1v[nt] = eb1[col];
    eb2v[nt] = eb2[col];
  }

  // gather thread mapping: 128 rows (64 src + 64 dst), 2 threads/row (64-short halves)
  const int grow = tid >> 1;
  const int ge = grow & 63;          // edge within tile
  const int gsd = grow >> 6;         // 0=src, 1=dst
  const int gpos = (ge << 1) | gsd;  // position in tile's 128 packed ints
  const int ghalf = tid & 1;
  const int et = tid >> 2, q = tid & 3;  // E staging: 4 threads/edge

  // per-thread fetch of a 64-short half-row -> 8 bf16x8
#define GATHER8(node, v0, v1, v2, v3, v4, v5, v6, v7)                                   \
  if (XBF) {                                                                            \
    const bf16x8* gp = reinterpret_cast<const bf16x8*>(Xbf_b + (size_t)(node)*128 + ghalf*64); \
    v0 = gp[0]; v1 = gp[1]; v2 = gp[2]; v3 = gp[3];                                     \
    v4 = gp[4]; v5 = gp[5]; v6 = gp[6]; v7 = gp[7];                                     \
  } else {                                                                              \
    const float4* gp = reinterpret_cast<const float4*>(X_b + (size_t)(node)*128 + ghalf*64); \
    v0 = pack2(gp[0], gp[1]);  v1 = pack2(gp[2], gp[3]);                                \
    v2 = pack2(gp[4], gp[5]);  v3 = pack2(gp[6], gp[7]);                                \
    v4 = pack2(gp[8], gp[9]);  v5 = pack2(gp[10], gp[11]);                              \
    v6 = pack2(gp[12], gp[13]); v7 = pack2(gp[14], gp[15]);                             \
  }

#define STORE8(v0, v1, v2, v3, v4, v5, v6, v7)                                          \
  {                                                                                     \
    bf16x8* aw8 = reinterpret_cast<bf16x8*>(&A_lds[ge * 296 + gsd * 128 + ghalf * 64]); \
    aw8[0] = v0; aw8[1] = v1; aw8[2] = v2; aw8[3] = v3;                                 \
    aw8[4] = v4; aw8[5] = v5; aw8[6] = v6; aw8[7] = v7;                                 \
  }

  // ---------- prologue: stage tile0 fully, idx[tile1] ----------
  if (tid < 64) {  // zero pad k=272..287 (never rewritten)
    bf16x8 z = {0, 0, 0, 0, 0, 0, 0, 0};
    *reinterpret_cast<bf16x8*>(&A_lds[tid * 296 + 272]) = z;
    *reinterpret_cast<bf16x8*>(&A_lds[tid * 296 + 280]) = z;
  }
  {
    const int e0 = tile0 * 64;
    int node = edges_b[(size_t)e0 * 2 + gpos];
    bf16x8 s0, s1, s2, s3, s4, s5, s6, s7;
    GATHER8(node, s0, s1, s2, s3, s4, s5, s6, s7);
    STORE8(s0, s1, s2, s3, s4, s5, s6, s7);
    float4 ev = *reinterpret_cast<const float4*>(E_b + (size_t)e0 * 16 + tid * 4);
    ushort4 evb; evb.x = f2bf(ev.x); evb.y = f2bf(ev.y); evb.z = f2bf(ev.z); evb.w = f2bf(ev.w);
    *reinterpret_cast<ushort4*>(&A_lds[et * 296 + 256 + q * 4]) = evb;
    if (q == 0) gate_lds[0][et] = fminf(fmaxf(1.f + gs * ev.z, 0.f), 3.f);
    if (tid < 128) idx_lds[1][tid] = edges_b[(size_t)(tile0 + 1) * 64 * 2 + tid];
  }
  __syncthreads();

  float accm0 = 0.f, accm1 = 0.f, accp0 = 0.f, accp1 = 0.f, accg = 0.f;
  const f32x4 zf = {0.f, 0.f, 0.f, 0.f};

  for (int it = 0; it < NT; ++it) {
    const int cur = it & 1, nxt = (it + 1) & 1;
    const bool hasn1 = (it + 1 < NT);
    const bool hasn2 = (it + 2 < NT);
    const int e0n = (hasn1 ? (tile0 + it + 1) : tile0) * 64;
    const int e0n2 = (hasn2 ? (tile0 + it + 2) : tile0) * 64;

    // ---- phase A: issue prefetches for t+1 / t+2 ----
    float4 epre = *reinterpret_cast<const float4*>(E_b + (size_t)e0n * 16 + tid * 4);
    int idxpre = 0;
    if (tid < 128) idxpre = edges_b[(size_t)e0n2 * 2 + tid];
    const int node = idx_lds[nxt][gpos];
    bf16x8 p0v, p1v, p2v, p3v, p4v, p5v, p6v, p7v;
    GATHER8(node, p0v, p1v, p2v, p3v, p4v, p5v, p6v, p7v);

    // ---- layer 1 on tile t (K=288) + pW contribution ----
#pragma unroll
    for (int rt = 0; rt < 4; ++rt) {
      const short* arow = &A_lds[(rt * 16 + fc) * 296 + fg * 8];
      f32x4 a0 = zf, a1 = zf;
#pragma unroll
      for (int kt = 0; kt < 9; ++kt) {
        bf16x8 av = *reinterpret_cast<const bf16x8*>(arow + kt * 32);
        a0 = mfma16(av, B1[0][kt], a0);
        a1 = mfma16(av, B1[1][kt], a1);
      }
      bf16x8 av8 = *reinterpret_cast<const bf16x8*>(arow + 256);
      f32x4 q0 = mfma16(av8, PWf[0], zf);
      f32x4 q1 = mfma16(av8, PWf[1], zf);
#pragma unroll
      for (int r = 0; r < 4; ++r) {
        int row = rt * 16 + fg * 4 + r;
        float g = gate_lds[cur][row];
        accp0 += q0[r] * g;
        accp1 += q1[r] * g;
        h1_lds[row * 136 + ncol0 + fc] = (short)f2bf(fmaxf(a0[r] + eb1v[0], 0.f));
        h1_lds[row * 136 + ncol0 + 16 + fc] = (short)f2bf(fmaxf(a1[r] + eb1v[1], 0.f));
      }
    }
    __syncthreads();  // barrier1: h1 ready; A_lds reads of tile t complete

    // ---- phase B: drain prefetch into LDS (tile t+1) ----
    if (hasn1) {
      STORE8(p0v, p1v, p2v, p3v, p4v, p5v, p6v, p7v);
      ushort4 evb; evb.x = f2bf(epre.x); evb.y = f2bf(epre.y); evb.z = f2bf(epre.z); evb.w = f2bf(epre.w);
      *reinterpret_cast<ushort4*>(&A_lds[et * 296 + 256 + q * 4]) = evb;
      if (q == 0) gate_lds[nxt][et] = fminf(fmaxf(1.f + gs * epre.z, 0.f), 3.f);
      if (tid < 128) idx_lds[cur][tid] = idxpre;
    }

    // ---- layer 2 on tile t (K=128) ----
    if (w == 0) accg += gate_lds[cur][lane];
#pragma unroll
    for (int rt = 0; rt < 4; ++rt) {
      const short* hrow = &h1_lds[(rt * 16 + fc) * 136 + fg * 8];
      f32x4 a0 = zf, a1 = zf;
#pragma unroll
      for (int kt = 0; kt < 4; ++kt) {
        bf16x8 hv = *reinterpret_cast<const bf16x8*>(hrow + kt * 32);
        a0 = mfma16(hv, B2[0][kt], a0);
        a1 = mfma16(hv, B2[1][kt], a1);
      }
#pragma unroll
      for (int r = 0; r < 4; ++r) {
        int row = rt * 16 + fg * 4 + r;
        float g = gate_lds[cur][row];
        accm0 += fmaxf(a0[r] + eb2v[0], 0.f) * g;
        accm1 += fmaxf(a1[r] + eb2v[1], 0.f) * g;
      }
    }
    __syncthreads();  // barrier2: A_lds[t+1]/gate/idx ready; h1 free
  }

  // ---- reduce over fg groups, striped atomics ----
  accm0 += __shfl_xor(accm0, 16); accm0 += __shfl_xor(accm0, 32);
  accm1 += __shfl_xor(accm1, 16); accm1 += __shfl_xor(accm1, 32);
  accp0 += __shfl_xor(accp0, 16); accp0 += __shfl_xor(accp0, 32);
  accp1 += __shfl_xor(accp1, 16); accp1 += __shfl_xor(accp1, 32);
  const int stripe = blockIdx.x & (STRIPES - 1);
  float* base = edge_acc + ((size_t)b * STRIPES + stripe) * 264;
  if (fg == 0) {
    atomicAdd(base + ncol0 + fc, accm0);
    atomicAdd(base + ncol0 + 16 + fc, accm1);
    atomicAdd(base + 128 + ncol0 + fc, accp0);
    atomicAdd(base + 128 + ncol0 + 16 + fc, accp1);
  }
  if (w == 0) {
#pragma unroll
    for (int off = 1; off < 64; off <<= 1) accg += __shfl_xor(accg, off);
    if (lane == 0) atomicAdd(base + 256, accg);
  }
#undef GATHER8
#undef STORE8
}

// ---------------- final combine + readout head (exact f32) ----------------

__global__ void final_kernel(const float* __restrict__ edge_acc, const float* __restrict__ node_acc,
                             const float* __restrict__ pb, const float* __restrict__ rW1,
                             const float* __restrict__ rb1, const float* __restrict__ rW2,
                             const float* __restrict__ rb2, float* __restrict__ out) {
  int b = blockIdx.x;
  int j = threadIdx.x;  // 0..127
  __shared__ float feat[256];
  __shared__ float h[64];
  const float* ea = edge_acc + (size_t)b * STRIPES * 264;
  const float* na = node_acc + (size_t)b * STRIPES * 128;
  float ms = 0.f, ps = 0.f, hs = 0.f, gsum = 0.f;
  for (int s = 0; s < STRIPES; ++s) {
    ms += ea[s * 264 + j];
    ps += ea[s * 264 + 128 + j];
    hs += na[s * 128 + j];
    gsum += ea[s * 264 + 256];
  }
  feat[j] = (hs + 2.f * ms) * (1.f / (float)NN);  // H.mean = Hx.mean + 2*sum_m/N
  feat[128 + j] = (ps + gsum * pb[j]) / ((float)ME + 1e-6f);
  __syncthreads();
  if (j < 64) {
    float a = rb1[j];
    for (int i = 0; i < 256; ++i) a += feat[i] * rW1[i * 64 + j];
    h[j] = fmaxf(a, 0.f);
  }
  __syncthreads();
  if (j < 2) {
    float a = rb2[j];
    for (int i = 0; i < 64; ++i) a += h[i] * rW2[i * 2 + j];
    out[b * 2 + j] = a;
  }
}

// ---------------- host ----------------

extern "C" void kernel_launch(void* const* d_in, const int* in_sizes, int n_in,
                              void* d_out, int out_size, void* d_ws, size_t ws_size,
                              hipStream_t stream) {
  const float* X = (const float*)d_in[0];
  const float* E = (const float*)d_in[1];
  const int* edges = (const int*)d_in[2];
  const float* nW1 = (const float*)d_in[3];
  const float* nb1 = (const float*)d_in[4];
  const float* nW2 = (const float*)d_in[5];
  const float* nb2 = (const float*)d_in[6];
  const float* eW1 = (const float*)d_in[7];
  const float* eb1 = (const float*)d_in[8];
  const float* eW2 = (const float*)d_in[9];
  const float* eb2 = (const float*)d_in[10];
  const float* pW = (const float*)d_in[11];
  const float* pb = (const float*)d_in[12];
  const float* rW1 = (const float*)d_in[13];
  const float* rb1 = (const float*)d_in[14];
  const float* rW2 = (const float*)d_in[15];
  const float* rb2 = (const float*)d_in[16];
  const float* gscale = (const float*)d_in[17];
  float* out = (float*)d_out;

  char* ws = (char*)d_ws;
  size_t off = 0;
  auto alloc = [&](size_t sz) -> void* {
    void* p = ws + off;
    off = (off + sz + 255) & ~(size_t)255;
    return p;
  };
  short* ew1T = (short*)alloc(288 * 128 * 2);
  short* ew2T = (short*)alloc(128 * 128 * 2);
  short* nw1T = (short*)alloc(128 * 128 * 2);
  short* nw2T = (short*)alloc(128 * 128 * 2);
  short* pwT  = (short*)alloc(32 * 128 * 2);
  size_t acc_floats = (size_t)NB * STRIPES * 264 + (size_t)NB * STRIPES * 128;
  float* acc = (float*)alloc(acc_floats * 4);
  float* edge_acc = acc;
  float* node_acc = acc + (size_t)NB * STRIPES * 264;
  size_t xbf_bytes = (size_t)NB * NN * 128 * 2;
  size_t off_before_xbf = off;
  short* Xbf = (short*)alloc(xbf_bytes);
  bool use_xbf = (off_before_xbf + xbf_bytes) <= ws_size;

  hipMemsetAsync(acc, 0, acc_floats * 4, stream);
  prep_w_kernel<<<dim3(128), dim3(256), 0, stream>>>(eW1, eW2, nW1, nW2, pW,
                                                     ew1T, ew2T, nw1T, nw2T, pwT);
  if (use_xbf) {
    node_kernel<true><<<dim3(313, 2), dim3(256), 0, stream>>>(X, Xbf, nw1T, nw2T, nb1, nb2, node_acc);
    edge_kernel<true><<<dim3(625, 2), dim3(256), 0, stream>>>(
        Xbf, X, E, edges, ew1T, ew2T, pwT, eb1, eb2, gscale, edge_acc);
  } else {
    node_kernel<false><<<dim3(313, 2), dim3(256), 0, stream>>>(X, Xbf, nw1T, nw2T, nb1, nb2, node_acc);
    edge_kernel<false><<<dim3(625, 2), dim3(256), 0, stream>>>(
        Xbf, X, E, edges, ew1T, ew2T, pwT, eb1, eb2, gscale, edge_acc);
  }
  final_kernel<<<dim3(NB), dim3(128), 0, stream>>>(edge_acc, node_acc, pb, rW1, rb1, rW2, rb2, out);
}